// Round 1
// baseline (977.118 us; speedup 1.0000x reference)
//
#include <hip/hip_runtime.h>
#include <math.h>

#define Bb   4
#define Cc   256
#define Hh   48
#define Ww   48
#define NNp  2304          // H*W
#define NHd  4
#define HDd  64
#define KDd  32
#define QKVC 512
#define FFC  512
#define EPSf 1e-3f

// ---------------------------------------------------------------------------
// Generic fused 1x1-conv GEMM:  Y[b,oc,n] = epi( sum_c W[oc,c] * X[b,c,n] )
// MODE 0: BN only   MODE 1: BN + residual   MODE 2: BN + SiLU
// Tiles: 64x64 output, BK=16. 256 threads, 4x4 per thread.
// ---------------------------------------------------------------------------
template<int MODE>
__global__ __launch_bounds__(256)
void gemm_bn(const float* __restrict__ Wm, const float* __restrict__ X,
             float* __restrict__ Y,
             const float* __restrict__ bng, const float* __restrict__ bnb,
             const float* __restrict__ bnm, const float* __restrict__ bnv,
             const float* __restrict__ res,
             int M, int K)
{
    const int b  = blockIdx.z;
    const int n0 = blockIdx.x * 64;
    const int m0 = blockIdx.y * 64;
    const float* Xb = X + (size_t)b * K * NNp;

    __shared__ float Ws[16][68];   // [kk][m] transposed W tile, padded
    __shared__ float Xs[16][64];   // [kk][n]

    const int tid = threadIdx.x;
    const int tx = tid & 15, ty = tid >> 4;

    float acc[4][4];
    #pragma unroll
    for (int i = 0; i < 4; ++i)
        #pragma unroll
        for (int j = 0; j < 4; ++j) acc[i][j] = 0.f;

    for (int k0 = 0; k0 < K; k0 += 16) {
        {   // W tile: 64 rows x 16 k, float4 along K, scatter-transpose
            const int r  = tid >> 2;          // 0..63
            const int kk = (tid & 3) * 4;     // 0,4,8,12
            const float4 wv = *(const float4*)(Wm + (size_t)(m0 + r) * K + k0 + kk);
            Ws[kk + 0][r] = wv.x; Ws[kk + 1][r] = wv.y;
            Ws[kk + 2][r] = wv.z; Ws[kk + 3][r] = wv.w;
        }
        {   // X tile: 16 k x 64 n, float4 along n (coalesced)
            const int kk = tid >> 4;          // 0..15
            const int c  = (tid & 15) * 4;
            *(float4*)&Xs[kk][c] = *(const float4*)(Xb + (size_t)(k0 + kk) * NNp + n0 + c);
        }
        __syncthreads();
        #pragma unroll
        for (int kk = 0; kk < 16; ++kk) {
            float av[4], bv[4];
            *(float4*)av = *(const float4*)&Ws[kk][ty * 4];
            *(float4*)bv = *(const float4*)&Xs[kk][tx * 4];
            #pragma unroll
            for (int i = 0; i < 4; ++i)
                #pragma unroll
                for (int j = 0; j < 4; ++j)
                    acc[i][j] += av[i] * bv[j];
        }
        __syncthreads();
    }

    #pragma unroll
    for (int i = 0; i < 4; ++i) {
        const int oc = m0 + ty * 4 + i;
        const float s = bng[oc] * rsqrtf(bnv[oc] + EPSf);
        const float t = bnb[oc] - bnm[oc] * s;
        const size_t base = (size_t)b * M * NNp + (size_t)oc * NNp + n0 + tx * 4;
        #pragma unroll
        for (int j = 0; j < 4; ++j) {
            float y = acc[i][j] * s + t;
            if (MODE == 1) y += res[base + j];
            if (MODE == 2) y = y / (1.f + __expf(-y));
            Y[base + j] = y;
        }
    }
}

// ---------------------------------------------------------------------------
// Flash-style attention. One WG per (query-tile of 64, head, batch).
// 256 threads: row = tid/4 (query row in tile), quad = tid%4 (key-col split).
// Online softmax over all 2304 keys in tiles of 64. fp32.
// qkv layout: (b, 512, n); head h: q at ch h*128, k at +32, v at +64.
// ---------------------------------------------------------------------------
__global__ __launch_bounds__(256)
void attn_kernel(const float* __restrict__ qkv, float* __restrict__ obuf)
{
    const int qt = blockIdx.x;
    const int h  = blockIdx.y;
    const int b  = blockIdx.z;
    const int n0 = qt * 64;

    const float* base = qkv + (size_t)b * QKVC * NNp + (size_t)h * 128 * NNp;
    const float* qp = base;
    const float* kp = base + (size_t)32 * NNp;
    const float* vp = base + (size_t)64 * NNp;

    __shared__ float qs[32][64];
    __shared__ float ks[32][64];
    __shared__ float vs[64][64];

    const int tid  = threadIdx.x;
    const int row  = tid >> 2;
    const int quad = tid & 3;

    const float scale = 0.17677669529663687f;   // 1/sqrt(32)

    #pragma unroll
    for (int l = 0; l < 8; ++l) {               // q tile, pre-scaled
        const int idx = tid + l * 256;
        qs[idx >> 6][idx & 63] = qp[(size_t)(idx >> 6) * NNp + n0 + (idx & 63)] * scale;
    }

    float m_run = -1e30f, l_run = 0.f;
    float o[64];
    #pragma unroll
    for (int d = 0; d < 64; ++d) o[d] = 0.f;

    for (int m0 = 0; m0 < NNp; m0 += 64) {
        __syncthreads();                        // previous tile fully consumed
        #pragma unroll
        for (int l = 0; l < 8; ++l) {
            const int idx = tid + l * 256;
            ks[idx >> 6][idx & 63] = kp[(size_t)(idx >> 6) * NNp + m0 + (idx & 63)];
        }
        #pragma unroll
        for (int l = 0; l < 16; ++l) {
            const int idx = tid + l * 256;
            vs[idx >> 6][idx & 63] = vp[(size_t)(idx >> 6) * NNp + m0 + (idx & 63)];
        }
        __syncthreads();

        // S = q^T k for my row, my 16 key columns
        float s[16];
        #pragma unroll
        for (int j = 0; j < 16; ++j) s[j] = 0.f;
        #pragma unroll 8
        for (int kd = 0; kd < 32; ++kd) {
            const float qv = qs[kd][row];
            const float4* krow = (const float4*)&ks[kd][quad * 16];
            #pragma unroll
            for (int jj = 0; jj < 4; ++jj) {
                const float4 kv = krow[jj];
                s[jj * 4 + 0] += qv * kv.x;  s[jj * 4 + 1] += qv * kv.y;
                s[jj * 4 + 2] += qv * kv.z;  s[jj * 4 + 3] += qv * kv.w;
            }
        }

        float tmax = s[0];
        #pragma unroll
        for (int j = 1; j < 16; ++j) tmax = fmaxf(tmax, s[j]);
        tmax = fmaxf(tmax, __shfl_xor(tmax, 1));
        tmax = fmaxf(tmax, __shfl_xor(tmax, 2));

        const float mnew = fmaxf(m_run, tmax);
        const float fac  = __expf(m_run - mnew);
        float p[16], psum = 0.f;
        #pragma unroll
        for (int j = 0; j < 16; ++j) { p[j] = __expf(s[j] - mnew); psum += p[j]; }
        l_run = l_run * fac + psum;
        m_run = mnew;

        #pragma unroll
        for (int d = 0; d < 64; ++d) {
            float a = o[d] * fac;
            const float4* vrow = (const float4*)&vs[d][quad * 16];
            #pragma unroll
            for (int jj = 0; jj < 4; ++jj) {
                const float4 vv = vrow[jj];
                a += p[jj * 4 + 0] * vv.x + p[jj * 4 + 1] * vv.y
                   + p[jj * 4 + 2] * vv.z + p[jj * 4 + 3] * vv.w;
            }
            o[d] = a;
        }
    }

    // reduce partial l and o across the 4 quads of each row
    float lt = l_run;
    lt += __shfl_xor(lt, 1);
    lt += __shfl_xor(lt, 2);
    const float inv = 1.f / lt;

    float st[16];
    #pragma unroll
    for (int d = 0; d < 64; ++d) {
        float val = o[d];
        val += __shfl_xor(val, 1);
        val += __shfl_xor(val, 2);
        if ((d >> 4) == quad) st[d & 15] = val * inv;
    }
    float* ob = obuf + (size_t)b * Cc * NNp + (size_t)(h * 64) * NNp + n0 + row;
    #pragma unroll
    for (int j = 0; j < 16; ++j)
        ob[(size_t)(quad * 16 + j) * NNp] = st[j];
}

// ---------------------------------------------------------------------------
// Depthwise 3x3 conv on v (+BN), accumulated into obuf (o + pe).
// ---------------------------------------------------------------------------
__global__ __launch_bounds__(256)
void pe_bn_add(const float* __restrict__ qkv, const float* __restrict__ pw,
               const float* __restrict__ g, const float* __restrict__ bb,
               const float* __restrict__ mm, const float* __restrict__ vv,
               float* __restrict__ obuf)
{
    const int p = blockIdx.x * 256 + threadIdx.x;   // 0..2303
    const int c = blockIdx.y;
    const int b = blockIdx.z;
    if (p >= NNp) return;
    const int yy = p / Ww, xx = p - yy * Ww;

    const float* vch = qkv + ((size_t)b * QKVC + (size_t)((c >> 6) * 128 + 64 + (c & 63))) * NNp;
    float acc = 0.f;
    #pragma unroll
    for (int dy = -1; dy <= 1; ++dy)
        #pragma unroll
        for (int dx = -1; dx <= 1; ++dx) {
            const int Y = yy + dy, X = xx + dx;
            if (Y >= 0 && Y < Hh && X >= 0 && X < Ww)
                acc += pw[c * 9 + (dy + 1) * 3 + (dx + 1)] * vch[Y * Ww + X];
        }
    const float s = g[c] * rsqrtf(vv[c] + EPSf);
    obuf[(size_t)b * Cc * NNp + (size_t)c * NNp + p] += acc * s + (bb[c] - mm[c] * s);
}

// ---------------------------------------------------------------------------
extern "C" void kernel_launch(void* const* d_in, const int* in_sizes, int n_in,
                              void* d_out, int out_size, void* d_ws, size_t ws_size,
                              hipStream_t stream)
{
    const float* x      = (const float*)d_in[0];
    const float* qkv_w  = (const float*)d_in[1];
    const float* qkv_g  = (const float*)d_in[2];
    const float* qkv_b  = (const float*)d_in[3];
    const float* qkv_m  = (const float*)d_in[4];
    const float* qkv_v  = (const float*)d_in[5];
    const float* pe_w   = (const float*)d_in[6];
    const float* pe_g   = (const float*)d_in[7];
    const float* pe_b   = (const float*)d_in[8];
    const float* pe_m   = (const float*)d_in[9];
    const float* pe_v   = (const float*)d_in[10];
    const float* proj_w = (const float*)d_in[11];
    const float* proj_g = (const float*)d_in[12];
    const float* proj_b = (const float*)d_in[13];
    const float* proj_m = (const float*)d_in[14];
    const float* proj_v = (const float*)d_in[15];
    const float* f1_w   = (const float*)d_in[16];
    const float* f1_g   = (const float*)d_in[17];
    const float* f1_b   = (const float*)d_in[18];
    const float* f1_m   = (const float*)d_in[19];
    const float* f1_v   = (const float*)d_in[20];
    const float* f2_w   = (const float*)d_in[21];
    const float* f2_g   = (const float*)d_in[22];
    const float* f2_b   = (const float*)d_in[23];
    const float* f2_m   = (const float*)d_in[24];
    const float* f2_v   = (const float*)d_in[25];

    float* ws   = (float*)d_ws;
    float* qkvb = ws;                                   // 4*512*2304 = 4,718,592 f
    float* obuf = ws + (size_t)4718592;                 // 4*256*2304 = 2,359,296 f
    float* x1   = ws + (size_t)4718592 + 2359296;       // 2,359,296 f
    float* fbuf = ws;                                   // aliases qkvb (dead by then)
    float* out  = (float*)d_out;

    const dim3 blk(256);

    // 1) qkv = BN(conv1x1(x, qkv_w))               M=512 K=256
    gemm_bn<0><<<dim3(36, 8, 4), blk, 0, stream>>>(qkv_w, x, qkvb,
        qkv_g, qkv_b, qkv_m, qkv_v, nullptr, QKVC, Cc);

    // 2) o = attention(q,k,v)
    attn_kernel<<<dim3(36, 4, 4), blk, 0, stream>>>(qkvb, obuf);

    // 3) o += BN(dwconv3x3(v, pe_w))
    pe_bn_add<<<dim3(9, 256, 4), blk, 0, stream>>>(qkvb, pe_w,
        pe_g, pe_b, pe_m, pe_v, obuf);

    // 4) x1 = x + BN(conv1x1(o+pe, proj_w))        M=256 K=256
    gemm_bn<1><<<dim3(36, 4, 4), blk, 0, stream>>>(proj_w, obuf, x1,
        proj_g, proj_b, proj_m, proj_v, x, Cc, Cc);

    // 5) f = SiLU(BN(conv1x1(x1, f1_w)))           M=512 K=256
    gemm_bn<2><<<dim3(36, 8, 4), blk, 0, stream>>>(f1_w, x1, fbuf,
        f1_g, f1_b, f1_m, f1_v, nullptr, FFC, Cc);

    // 6) out = x1 + BN(conv1x1(f, f2_w))           M=256 K=512
    gemm_bn<1><<<dim3(36, 4, 4), blk, 0, stream>>>(f2_w, fbuf, out,
        f2_g, f2_b, f2_m, f2_v, x1, Cc, FFC);
}

// Round 2
// 292.016 us; speedup vs baseline: 3.3461x; 3.3461x over previous
//
#include <hip/hip_runtime.h>
#include <math.h>

#define Bb   4
#define Cc   256
#define Hh   48
#define Ww   48
#define NNp  2304          // H*W
#define NHd  4
#define HDd  64
#define KDd  32
#define QKVC 512
#define FFC  512
#define EPSf 1e-3f

typedef unsigned int  u32;
typedef unsigned short u16;
typedef __attribute__((ext_vector_type(8))) __bf16 bf16x8;
typedef __attribute__((ext_vector_type(4))) float  f32x4;

__device__ __forceinline__ u16 f2bf(float f) {
    u32 u = __float_as_uint(f);
    u = (u + 0x7fffu + ((u >> 16) & 1u)) >> 16;
    return (u16)u;
}

__device__ __forceinline__ void gload16(const void* gsrc, void* ldst) {
    __builtin_amdgcn_global_load_lds(
        (const __attribute__((address_space(1))) u32*)gsrc,
        (__attribute__((address_space(3))) u32*)ldst, 16, 0, 0);
}

// ---------------------------------------------------------------------------
// fp32 tiled GEMM with fused BN epilogues (unchanged from R1).
// MODE 0: BN   MODE 1: BN+residual   MODE 2: BN+SiLU
// ---------------------------------------------------------------------------
template<int MODE>
__global__ __launch_bounds__(256)
void gemm_bn(const float* __restrict__ Wm, const float* __restrict__ X,
             float* __restrict__ Y,
             const float* __restrict__ bng, const float* __restrict__ bnb,
             const float* __restrict__ bnm, const float* __restrict__ bnv,
             const float* __restrict__ res,
             int M, int K)
{
    const int b  = blockIdx.z;
    const int n0 = blockIdx.x * 64;
    const int m0 = blockIdx.y * 64;
    const float* Xb = X + (size_t)b * K * NNp;

    __shared__ float Ws[16][68];
    __shared__ float Xs[16][64];

    const int tid = threadIdx.x;
    const int tx = tid & 15, ty = tid >> 4;

    float acc[4][4];
    #pragma unroll
    for (int i = 0; i < 4; ++i)
        #pragma unroll
        for (int j = 0; j < 4; ++j) acc[i][j] = 0.f;

    for (int k0 = 0; k0 < K; k0 += 16) {
        {
            const int r  = tid >> 2;
            const int kk = (tid & 3) * 4;
            const float4 wv = *(const float4*)(Wm + (size_t)(m0 + r) * K + k0 + kk);
            Ws[kk + 0][r] = wv.x; Ws[kk + 1][r] = wv.y;
            Ws[kk + 2][r] = wv.z; Ws[kk + 3][r] = wv.w;
        }
        {
            const int kk = tid >> 4;
            const int c  = (tid & 15) * 4;
            *(float4*)&Xs[kk][c] = *(const float4*)(Xb + (size_t)(k0 + kk) * NNp + n0 + c);
        }
        __syncthreads();
        #pragma unroll
        for (int kk = 0; kk < 16; ++kk) {
            float av[4], bv[4];
            *(float4*)av = *(const float4*)&Ws[kk][ty * 4];
            *(float4*)bv = *(const float4*)&Xs[kk][tx * 4];
            #pragma unroll
            for (int i = 0; i < 4; ++i)
                #pragma unroll
                for (int j = 0; j < 4; ++j)
                    acc[i][j] += av[i] * bv[j];
        }
        __syncthreads();
    }

    #pragma unroll
    for (int i = 0; i < 4; ++i) {
        const int oc = m0 + ty * 4 + i;
        const float s = bng[oc] * rsqrtf(bnv[oc] + EPSf);
        const float t = bnb[oc] - bnm[oc] * s;
        const size_t base = (size_t)b * M * NNp + (size_t)oc * NNp + n0 + tx * 4;
        #pragma unroll
        for (int j = 0; j < 4; ++j) {
            float y = acc[i][j] * s + t;
            if (MODE == 1) y += res[base + j];
            if (MODE == 2) y = y / (1.f + __expf(-y));
            Y[base + j] = y;
        }
    }
}

// ---------------------------------------------------------------------------
// Repack qkv fp32 -> bf16: Qt[n][32] (pre-scaled), Kt[m][32], Vb[d][m].
// ---------------------------------------------------------------------------
__global__ __launch_bounds__(256)
void repack(const float* __restrict__ qkv,
            u16* __restrict__ Qt, u16* __restrict__ Kt, u16* __restrict__ Vb)
{
    const int n = blockIdx.x * 256 + threadIdx.x;
    const int h = blockIdx.y, b = blockIdx.z;
    const int bh = b * NHd + h;
    const float* base = qkv + ((size_t)b * QKVC + (size_t)h * 128) * NNp;
    const float scale = 0.17677669529663687f;   // 1/sqrt(32)

    u32 qw[16], kw[16];
    #pragma unroll
    for (int kk = 0; kk < 16; ++kk) {
        const float q0 = base[(size_t)(2*kk)   * NNp + n] * scale;
        const float q1 = base[(size_t)(2*kk+1) * NNp + n] * scale;
        const float k0 = base[(size_t)(32+2*kk)   * NNp + n];
        const float k1 = base[(size_t)(32+2*kk+1) * NNp + n];
        qw[kk] = (u32)f2bf(q0) | ((u32)f2bf(q1) << 16);
        kw[kk] = (u32)f2bf(k0) | ((u32)f2bf(k1) << 16);
    }
    u32* qd = (u32*)(Qt + ((size_t)bh * NNp + n) * 32);
    u32* kd = (u32*)(Kt + ((size_t)bh * NNp + n) * 32);
    #pragma unroll
    for (int c = 0; c < 4; ++c) {
        uint4 vq = make_uint4(qw[4*c], qw[4*c+1], qw[4*c+2], qw[4*c+3]);
        uint4 vk = make_uint4(kw[4*c], kw[4*c+1], kw[4*c+2], kw[4*c+3]);
        *(uint4*)(qd + 4*c) = vq;
        *(uint4*)(kd + 4*c) = vk;
    }

    const float* vsrc = base + (size_t)64 * NNp;
    u16* vd = Vb + (size_t)bh * 64 * NNp;
    #pragma unroll 8
    for (int d = 0; d < 64; ++d)
        vd[(size_t)d * NNp + n] = f2bf(vsrc[(size_t)d * NNp + n]);
}

// ---------------------------------------------------------------------------
// MFMA flash attention. 4 waves/WG, 16 queries/wave, key tiles of 64.
// S = mfma(Qfrag, Kfrag)  [D: row=q=(l>>4)*4+reg, col=key=l&15]
// PV = mfma(Vfrag, Pfrag) [D: row=d, col=q=l&15], O accumulated over tiles.
// ---------------------------------------------------------------------------
__global__ __launch_bounds__(256)
void attn_mfma(const u16* __restrict__ Qt, const u16* __restrict__ Kt,
               const u16* __restrict__ Vb, float* __restrict__ obuf)
{
    __shared__ __align__(16) u16 Klds[2][64 * 32];
    __shared__ __align__(16) u16 Vlds[2][64 * 64];
    __shared__ __align__(16) u16 Plds[4][16 * 64];
    __shared__ float Fac[4][16];

    const int tid  = threadIdx.x;
    const int wid  = tid >> 6;
    const int lane = tid & 63;
    const int g    = lane >> 4;
    const int i16  = lane & 15;

    const int h = blockIdx.y, b = blockIdx.z;
    const int bh = b * NHd + h;
    const u16* Qg = Qt + (size_t)bh * NNp * 32;
    const u16* Kg = Kt + (size_t)bh * NNp * 32;
    const u16* Vg = Vb + (size_t)bh * 64 * NNp;

    const int nq = blockIdx.x * 64 + wid * 16 + i16;
    const bf16x8 qfrag = *(const bf16x8*)(Qg + (size_t)nq * 32 + g * 8);

    f32x4 zero = {0.f, 0.f, 0.f, 0.f};
    f32x4 oacc[4];
    #pragma unroll
    for (int d = 0; d < 4; ++d) oacc[d] = zero;
    float m_run[4] = {-1e30f, -1e30f, -1e30f, -1e30f};
    float l_run[4] = {0.f, 0.f, 0.f, 0.f};

    // stage tile 0
    gload16(Kg + tid * 8, &Klds[0][tid * 8]);
    #pragma unroll
    for (int ii = 0; ii < 2; ++ii) {
        const int idx = ii * 256 + tid;
        const int d = idx >> 3, xx = idx & 7;
        const int c = xx ^ (d & 7);
        gload16(Vg + (size_t)d * NNp + c * 8, &Vlds[0][idx * 8]);
    }
    __syncthreads();

    int cur = 0;
    for (int t = 0; t < 36; ++t) {
        if (t < 35) {   // prefetch next tile into other buffer
            const int m0 = (t + 1) * 64;
            gload16(Kg + (size_t)m0 * 32 + tid * 8, &Klds[cur ^ 1][tid * 8]);
            #pragma unroll
            for (int ii = 0; ii < 2; ++ii) {
                const int idx = ii * 256 + tid;
                const int d = idx >> 3, xx = idx & 7;
                const int c = xx ^ (d & 7);
                gload16(Vg + (size_t)d * NNp + m0 + c * 8, &Vlds[cur ^ 1][idx * 8]);
            }
        }

        // ---- S = Q K^T : 4 MFMAs over key blocks of 16 ----
        f32x4 sac[4];
        #pragma unroll
        for (int j = 0; j < 4; ++j) {
            const bf16x8 kf = *(const bf16x8*)(&Klds[cur][(16 * j + i16) * 32 + g * 8]);
            sac[j] = __builtin_amdgcn_mfma_f32_16x16x32_bf16(qfrag, kf, zero, 0, 0, 0);
        }

        // ---- online softmax (rows n = g*4+r, cols m = 16j+i16) ----
        float p[4][4];
        float facr[4];
        #pragma unroll
        for (int r = 0; r < 4; ++r) {
            float m1 = fmaxf(fmaxf(sac[0][r], sac[1][r]), fmaxf(sac[2][r], sac[3][r]));
            m1 = fmaxf(m1, __shfl_xor(m1, 1));
            m1 = fmaxf(m1, __shfl_xor(m1, 2));
            m1 = fmaxf(m1, __shfl_xor(m1, 4));
            m1 = fmaxf(m1, __shfl_xor(m1, 8));
            const float mn = fmaxf(m_run[r], m1);
            const float fc = __expf(m_run[r] - mn);
            m_run[r] = mn;
            facr[r] = fc;
            float ps = 0.f;
            #pragma unroll
            for (int j = 0; j < 4; ++j) { p[j][r] = __expf(sac[j][r] - mn); ps += p[j][r]; }
            ps += __shfl_xor(ps, 1);
            ps += __shfl_xor(ps, 2);
            ps += __shfl_xor(ps, 4);
            ps += __shfl_xor(ps, 8);
            l_run[r] = l_run[r] * fc + ps;
        }

        // broadcast per-query rescale factor via LDS (n = g*4+r -> col n = l&15)
        if (i16 < 4) {
            const float fv = (i16 == 0) ? facr[0] : (i16 == 1) ? facr[1]
                           : (i16 == 2) ? facr[2] : facr[3];
            Fac[wid][g * 4 + i16] = fv;
        }

        // ---- P -> LDS bf16 (chunk-XOR swizzled) ----
        {
            u16* Pw = &Plds[wid][0];
            const int hi = i16 >> 3, lo = i16 & 7;
            #pragma unroll
            for (int r = 0; r < 4; ++r) {
                const int n  = g * 4 + r;
                const int vs = (g << 1) | (r & 1);
                #pragma unroll
                for (int j = 0; j < 4; ++j) {
                    const int ch = (2 * j + hi) ^ vs;
                    Pw[n * 64 + ch * 8 + lo] = f2bf(p[j][r]);
                }
            }
        }

        // rescale O
        const float facn = Fac[wid][i16];
        #pragma unroll
        for (int d = 0; d < 4; ++d) {
            oacc[d][0] *= facn; oacc[d][1] *= facn;
            oacc[d][2] *= facn; oacc[d][3] *= facn;
        }

        // ---- O += V * P^T : 2 m-halves x 4 d-blocks ----
        const int vswp = ((i16 >> 2) << 1) | (i16 & 1);
        const int d7   = i16 & 7;
        #pragma unroll
        for (int s = 0; s < 2; ++s) {
            const int pch = (4 * s + g) ^ vswp;
            const bf16x8 pf = *(const bf16x8*)(&Plds[wid][i16 * 64 + pch * 8]);
            const int vch = (4 * s + g) ^ d7;
            #pragma unroll
            for (int db = 0; db < 4; ++db) {
                const bf16x8 vf = *(const bf16x8*)(&Vlds[cur][(db * 16 + i16) * 64 + vch * 8]);
                oacc[db] = __builtin_amdgcn_mfma_f32_16x16x32_bf16(vf, pf, oacc[db], 0, 0, 0);
            }
        }

        __syncthreads();     // drains stage loads; next tile ready, cur consumed
        cur ^= 1;
    }

    // epilogue: 1/l broadcast + store
    if (i16 < 4) {
        const float lv = (i16 == 0) ? l_run[0] : (i16 == 1) ? l_run[1]
                       : (i16 == 2) ? l_run[2] : l_run[3];
        Fac[wid][g * 4 + i16] = 1.f / lv;
    }
    __syncthreads();
    const float linv = Fac[wid][i16];
    float* ob = obuf + ((size_t)b * Cc + (size_t)h * 64) * NNp + nq;
    #pragma unroll
    for (int db = 0; db < 4; ++db)
        #pragma unroll
        for (int r = 0; r < 4; ++r)
            ob[(size_t)(db * 16 + g * 4 + r) * NNp] = oacc[db][r] * linv;
}

// ---------------------------------------------------------------------------
// Depthwise 3x3 conv on v (+BN), accumulated into obuf.
// ---------------------------------------------------------------------------
__global__ __launch_bounds__(256)
void pe_bn_add(const float* __restrict__ qkv, const float* __restrict__ pw,
               const float* __restrict__ g, const float* __restrict__ bb,
               const float* __restrict__ mm, const float* __restrict__ vv,
               float* __restrict__ obuf)
{
    const int p = blockIdx.x * 256 + threadIdx.x;
    const int c = blockIdx.y;
    const int b = blockIdx.z;
    if (p >= NNp) return;
    const int yy = p / Ww, xx = p - yy * Ww;

    const float* vch = qkv + ((size_t)b * QKVC + (size_t)((c >> 6) * 128 + 64 + (c & 63))) * NNp;
    float acc = 0.f;
    #pragma unroll
    for (int dy = -1; dy <= 1; ++dy)
        #pragma unroll
        for (int dx = -1; dx <= 1; ++dx) {
            const int Y = yy + dy, X = xx + dx;
            if (Y >= 0 && Y < Hh && X >= 0 && X < Ww)
                acc += pw[c * 9 + (dy + 1) * 3 + (dx + 1)] * vch[Y * Ww + X];
        }
    const float s = g[c] * rsqrtf(vv[c] + EPSf);
    obuf[(size_t)b * Cc + (size_t)0 + 0] = obuf[(size_t)b * Cc + 0];  // placeholder avoided below
}

// NOTE: placeholder line above would be wrong — real implementation:
__global__ __launch_bounds__(256)
void pe_bn_add2(const float* __restrict__ qkv, const float* __restrict__ pw,
                const float* __restrict__ g, const float* __restrict__ bb,
                const float* __restrict__ mm, const float* __restrict__ vv,
                float* __restrict__ obuf)
{
    const int p = blockIdx.x * 256 + threadIdx.x;
    const int c = blockIdx.y;
    const int b = blockIdx.z;
    if (p >= NNp) return;
    const int yy = p / Ww, xx = p - yy * Ww;

    const float* vch = qkv + ((size_t)b * QKVC + (size_t)((c >> 6) * 128 + 64 + (c & 63))) * NNp;
    float acc = 0.f;
    #pragma unroll
    for (int dy = -1; dy <= 1; ++dy)
        #pragma unroll
        for (int dx = -1; dx <= 1; ++dx) {
            const int Y = yy + dy, X = xx + dx;
            if (Y >= 0 && Y < Hh && X >= 0 && X < Ww)
                acc += pw[c * 9 + (dy + 1) * 3 + (dx + 1)] * vch[Y * Ww + X];
        }
    const float s = g[c] * rsqrtf(vv[c] + EPSf);
    obuf[((size_t)b * Cc + c) * NNp + p] += acc * s + (bb[c] - mm[c] * s);
}

// ---------------------------------------------------------------------------
extern "C" void kernel_launch(void* const* d_in, const int* in_sizes, int n_in,
                              void* d_out, int out_size, void* d_ws, size_t ws_size,
                              hipStream_t stream)
{
    const float* x      = (const float*)d_in[0];
    const float* qkv_w  = (const float*)d_in[1];
    const float* qkv_g  = (const float*)d_in[2];
    const float* qkv_b  = (const float*)d_in[3];
    const float* qkv_m  = (const float*)d_in[4];
    const float* qkv_v  = (const float*)d_in[5];
    const float* pe_w   = (const float*)d_in[6];
    const float* pe_g   = (const float*)d_in[7];
    const float* pe_b   = (const float*)d_in[8];
    const float* pe_m   = (const float*)d_in[9];
    const float* pe_v   = (const float*)d_in[10];
    const float* proj_w = (const float*)d_in[11];
    const float* proj_g = (const float*)d_in[12];
    const float* proj_b = (const float*)d_in[13];
    const float* proj_m = (const float*)d_in[14];
    const float* proj_v = (const float*)d_in[15];
    const float* f1_w   = (const float*)d_in[16];
    const float* f1_g   = (const float*)d_in[17];
    const float* f1_b   = (const float*)d_in[18];
    const float* f1_m   = (const float*)d_in[19];
    const float* f1_v   = (const float*)d_in[20];
    const float* f2_w   = (const float*)d_in[21];
    const float* f2_g   = (const float*)d_in[22];
    const float* f2_b   = (const float*)d_in[23];
    const float* f2_m   = (const float*)d_in[24];
    const float* f2_v   = (const float*)d_in[25];

    char* wsb = (char*)d_ws;
    float* qkvb = (float*)wsb;                       // 18,874,368 B
    float* obuf = (float*)(wsb + 18874368);          //  9,437,184 B
    float* x1   = (float*)(wsb + 28311552);          //  9,437,184 B (aliases Qt/Kt, written after attn)
    u16*   Qt   = (u16*)(wsb + 28311552);            //  2,359,296 B
    u16*   Kt   = (u16*)(wsb + 28311552 + 2359296);  //  2,359,296 B
    u16*   Vb   = (u16*)(wsb + 28311552 + 4718592);  //  9,437,184 B
    float* fbuf = qkvb;                              // aliases qkvb (dead by step 5)
    float* out  = (float*)d_out;

    const dim3 blk(256);

    // 1) qkv = BN(conv1x1(x, qkv_w))
    gemm_bn<0><<<dim3(36, 8, 4), blk, 0, stream>>>(qkv_w, x, qkvb,
        qkv_g, qkv_b, qkv_m, qkv_v, nullptr, QKVC, Cc);

    // 1.5) repack to bf16 Qt/Kt/Vb
    repack<<<dim3(9, 4, 4), blk, 0, stream>>>(qkvb, Qt, Kt, Vb);

    // 2) o = attention(q,k,v)  (MFMA)
    attn_mfma<<<dim3(36, 4, 4), blk, 0, stream>>>(Qt, Kt, Vb, obuf);

    // 3) o += BN(dwconv3x3(v, pe_w))
    pe_bn_add2<<<dim3(9, 256, 4), blk, 0, stream>>>(qkvb, pe_w,
        pe_g, pe_b, pe_m, pe_v, obuf);

    // 4) x1 = x + BN(conv1x1(o+pe, proj_w))
    gemm_bn<1><<<dim3(36, 4, 4), blk, 0, stream>>>(proj_w, obuf, x1,
        proj_g, proj_b, proj_m, proj_v, x, Cc, Cc);

    // 5) f = SiLU(BN(conv1x1(x1, f1_w)))
    gemm_bn<2><<<dim3(36, 8, 4), blk, 0, stream>>>(f1_w, x1, fbuf,
        f1_g, f1_b, f1_m, f1_v, nullptr, FFC, Cc);

    // 6) out = x1 + BN(conv1x1(f, f2_w))
    gemm_bn<1><<<dim3(36, 4, 4), blk, 0, stream>>>(f2_w, fbuf, out,
        f2_g, f2_b, f2_m, f2_v, x1, Cc, FFC);
}

// Round 3
// 194.338 us; speedup vs baseline: 5.0279x; 1.5026x over previous
//
#include <hip/hip_runtime.h>
#include <math.h>

#define Bb   4
#define Cc   256
#define Hh   48
#define Ww   48
#define NNp  2304          // H*W
#define Rr   9216          // B*N
#define NHd  4
#define QKVC 512
#define EPSf 1e-3f

typedef unsigned int   u32;
typedef unsigned short u16;
typedef __attribute__((ext_vector_type(8))) __bf16 bf16x8;
typedef __attribute__((ext_vector_type(4))) float  f32x4;

__device__ __forceinline__ u16 f2bf(float f) {
    u32 u = __float_as_uint(f);
    u = (u + 0x7fffu + ((u >> 16) & 1u)) >> 16;
    return (u16)u;
}
__device__ __forceinline__ float bf2f(u16 h) {
    return __uint_as_float((u32)h << 16);
}
__device__ __forceinline__ void gload16(const void* gsrc, void* ldst) {
    __builtin_amdgcn_global_load_lds(
        (const __attribute__((address_space(1))) u32*)gsrc,
        (__attribute__((address_space(3))) u32*)ldst, 16, 0, 0);
}

// ---------------------------------------------------------------------------
// Weight prep: Wb[oc][k] = bf16(W*s*c), bias[oc] = (b - m*s)*c.
// qmode==1: c = 1/sqrt(32) for q channels (oc%128 < 32), else 1.
// ---------------------------------------------------------------------------
__global__ __launch_bounds__(64)
void prep_w(const float* __restrict__ W, const float* __restrict__ g,
            const float* __restrict__ b, const float* __restrict__ m,
            const float* __restrict__ v, u16* __restrict__ Wb,
            float* __restrict__ bias, int K, int qmode)
{
    const int oc = blockIdx.x;
    const int lane = threadIdx.x;
    const float s = g[oc] * rsqrtf(v[oc] + EPSf);
    const float c = (qmode == 1 && (oc & 127) < 32) ? 0.17677669529663687f : 1.f;
    if (lane == 0) bias[oc] = (b[oc] - m[oc] * s) * c;
    const float sc = s * c;
    for (int k0 = lane * 4; k0 < K; k0 += 256) {
        const float4 w = *(const float4*)(W + (size_t)oc * K + k0);
        u32 lo = (u32)f2bf(w.x * sc) | ((u32)f2bf(w.y * sc) << 16);
        u32 hi = (u32)f2bf(w.z * sc) | ((u32)f2bf(w.w * sc) << 16);
        *(uint2*)(Wb + (size_t)oc * K + k0) = make_uint2(lo, hi);
    }
}

// ---------------------------------------------------------------------------
// x (b,c,n) fp32 -> Xt [(b,n)][256] bf16 (transpose)
// ---------------------------------------------------------------------------
__global__ __launch_bounds__(256)
void cvt_x(const float* __restrict__ x, u16* __restrict__ Xt)
{
    const int b = blockIdx.z, c0 = blockIdx.y * 64, n0 = blockIdx.x * 64;
    __shared__ float tile[64][65];
    const int tid = threadIdx.x;
    {
        const int n = tid & 63, cl = tid >> 6;
        #pragma unroll
        for (int cc = 0; cc < 16; ++cc) {
            const int c = cc * 4 + cl;
            tile[c][n] = x[((size_t)b * Cc + c0 + c) * NNp + n0 + n];
        }
    }
    __syncthreads();
    {
        const int n = tid >> 2, q = tid & 3;
        #pragma unroll
        for (int j = 0; j < 2; ++j) {
            const int ch = q * 2 + j, c = ch * 8;
            u32 w[4];
            #pragma unroll
            for (int e = 0; e < 4; ++e)
                w[e] = (u32)f2bf(tile[c + 2*e][n]) | ((u32)f2bf(tile[c + 2*e + 1][n]) << 16);
            *(uint4*)(Xt + ((size_t)b * NNp + n0 + n) * Cc + c0 + c)
                = make_uint4(w[0], w[1], w[2], w[3]);
        }
    }
}

// ---------------------------------------------------------------------------
// MFMA GEMM:  Y[(b,n)][oc] = epi( sum_k Wb[oc][k] * Xt[(b,n)][k] )
// A=Wb rows (oc), B=Xt rows (n). 4 waves (2 oc x 2 n), BM=128, BK=32.
// MODE 0: bf16 out (qkv)      MODE 1: +x resid, fp32 out + bf16 out (proj)
// MODE 2: SiLU, bf16 out (f1) MODE 3: +resid, fp32 out only (f2)
// ---------------------------------------------------------------------------
template<int BN_, int FN_, int MODE>
__global__ __launch_bounds__(256)
void gemm_mfma(const u16* __restrict__ A, const u16* __restrict__ Bx,
               const float* __restrict__ bias, const float* __restrict__ resid,
               float* __restrict__ Yf, u16* __restrict__ Yt, int M, int K)
{
    constexpr int WN = FN_ * 16;
    const int r0 = blockIdx.x * BN_;
    const int m0 = blockIdx.y * 128;
    const int tid = threadIdx.x;
    const int lane = tid & 63, wid = tid >> 6;
    const int g = lane >> 4, i16 = lane & 15;
    const int wr = wid >> 1, wc = wid & 1;

    __shared__ __align__(16) u16 Al[4][128][8];
    __shared__ __align__(16) u16 Bl[4][BN_][8];

    f32x4 acc[4][FN_];
    #pragma unroll
    for (int i = 0; i < 4; ++i)
        #pragma unroll
        for (int j = 0; j < FN_; ++j) acc[i][j] = (f32x4){0.f, 0.f, 0.f, 0.f};

    for (int k0 = 0; k0 < K; k0 += 32) {
        #pragma unroll
        for (int ii = 0; ii < 2; ++ii) {
            const int ci = ii * 256 + tid;
            gload16(A + (size_t)(m0 + (ci & 127)) * K + k0 + (ci >> 7) * 8,
                    &Al[0][0][0] + (size_t)ci * 8);
        }
        if (BN_ == 128) {
            #pragma unroll
            for (int ii = 0; ii < 2; ++ii) {
                const int ci = ii * 256 + tid;
                gload16(Bx + (size_t)(r0 + (ci & 127)) * K + k0 + (ci >> 7) * 8,
                        &Bl[0][0][0] + (size_t)ci * 8);
            }
        } else {
            gload16(Bx + (size_t)(r0 + (tid & 63)) * K + k0 + (tid >> 6) * 8,
                    &Bl[0][0][0] + (size_t)tid * 8);
        }
        __syncthreads();
        bf16x8 af[4], bf[FN_];
        #pragma unroll
        for (int ao = 0; ao < 4; ++ao)
            af[ao] = *(const bf16x8*)&Al[g][wr * 64 + ao * 16 + i16][0];
        #pragma unroll
        for (int bo = 0; bo < FN_; ++bo)
            bf[bo] = *(const bf16x8*)&Bl[g][wc * WN + bo * 16 + i16][0];
        #pragma unroll
        for (int ao = 0; ao < 4; ++ao)
            #pragma unroll
            for (int bo = 0; bo < FN_; ++bo)
                acc[ao][bo] = __builtin_amdgcn_mfma_f32_16x16x32_bf16(
                    af[ao], bf[bo], acc[ao][bo], 0, 0, 0);
        __syncthreads();
    }

    const int b  = r0 / NNp;               // BN_ divides 2304
    const int nb = r0 - b * NNp;
    #pragma unroll
    for (int ao = 0; ao < 4; ++ao) {
        const int oc0 = m0 + wr * 64 + ao * 16 + g * 4;
        const float4 t4 = *(const float4*)(bias + oc0);
        #pragma unroll
        for (int bo = 0; bo < FN_; ++bo) {
            const int nloc = wc * WN + bo * 16 + i16;
            float y[4];
            y[0] = acc[ao][bo][0] + t4.x;  y[1] = acc[ao][bo][1] + t4.y;
            y[2] = acc[ao][bo][2] + t4.z;  y[3] = acc[ao][bo][3] + t4.w;
            if (MODE == 1 || MODE == 3) {
                const int n = nb + nloc;
                const size_t base = ((size_t)b * M + oc0) * NNp + n;
                #pragma unroll
                for (int r = 0; r < 4; ++r) {
                    y[r] += resid[base + (size_t)r * NNp];
                    Yf[base + (size_t)r * NNp] = y[r];
                }
            }
            if (MODE == 2) {
                #pragma unroll
                for (int r = 0; r < 4; ++r) y[r] = y[r] / (1.f + __expf(-y[r]));
            }
            if (MODE != 3) {
                const size_t rG = (size_t)(r0 + nloc);
                u32 lo = (u32)f2bf(y[0]) | ((u32)f2bf(y[1]) << 16);
                u32 hi = (u32)f2bf(y[2]) | ((u32)f2bf(y[3]) << 16);
                *(uint2*)(Yt + rG * M + oc0) = make_uint2(lo, hi);
            }
        }
    }
}

// ---------------------------------------------------------------------------
// V transpose: Yt [(b,n)][512] (v = ch h*128+64..127) -> Vb[bh][64][2304]
// ---------------------------------------------------------------------------
__global__ __launch_bounds__(256)
void repack_v(const u16* __restrict__ Yt, u16* __restrict__ Vb)
{
    const int m0 = blockIdx.x * 64;
    const int h = blockIdx.y, b = blockIdx.z;
    const int bh = b * NHd + h;
    __shared__ u16 vt[64][72];
    const int tid = threadIdx.x;
    #pragma unroll
    for (int ii = 0; ii < 2; ++ii) {
        const int mm = ii * 32 + (tid >> 3);
        const int ch = tid & 7;
        *(uint4*)&vt[mm][ch * 8] =
            *(const uint4*)(Yt + ((size_t)b * NNp + m0 + mm) * QKVC + h * 128 + 64 + ch * 8);
    }
    __syncthreads();
    const int d = tid >> 2, mq = tid & 3;
    #pragma unroll
    for (int j = 0; j < 2; ++j) {
        const int mc = mq * 2 + j;
        u32 w[4];
        #pragma unroll
        for (int e = 0; e < 4; ++e)
            w[e] = (u32)vt[mc * 8 + 2*e][d] | ((u32)vt[mc * 8 + 2*e + 1][d] << 16);
        *(uint4*)(Vb + ((size_t)bh * 64 + d) * NNp + m0 + mc * 8)
            = make_uint4(w[0], w[1], w[2], w[3]);
    }
}

// ---------------------------------------------------------------------------
// MFMA flash attention. Q/K from Yt bf16 rows; V from Vb [d][m].
// Output Ot bf16 [(b,n)][256].
// ---------------------------------------------------------------------------
__global__ __launch_bounds__(256)
void attn_mfma(const u16* __restrict__ Yt, const u16* __restrict__ Vb,
               u16* __restrict__ Ot)
{
    __shared__ __align__(16) u16 Klds[2][4][64][8];
    __shared__ __align__(16) u16 Vlds[2][64 * 64];
    __shared__ __align__(16) u16 Plds[4][16][72];
    __shared__ float Fac[4][16];

    const int tid  = threadIdx.x;
    const int wid  = tid >> 6;
    const int lane = tid & 63;
    const int g    = lane >> 4;
    const int i16  = lane & 15;

    const int h = blockIdx.y, b = blockIdx.z;
    const int bh = b * NHd + h;
    const size_t bG = (size_t)b * NNp;
    const u16* Vg = Vb + (size_t)bh * 64 * NNp;

    const int nq = blockIdx.x * 64 + wid * 16 + i16;
    const bf16x8 qfrag = *(const bf16x8*)(Yt + (bG + nq) * QKVC + h * 128 + g * 8);

    f32x4 zero = {0.f, 0.f, 0.f, 0.f};
    f32x4 oacc[4];
    #pragma unroll
    for (int d = 0; d < 4; ++d) oacc[d] = zero;
    float m_run[4] = {-1e30f, -1e30f, -1e30f, -1e30f};
    float l_run[4] = {0.f, 0.f, 0.f, 0.f};

    // stage tile 0
    gload16(Yt + (bG + (tid & 63)) * QKVC + h * 128 + 32 + (tid >> 6) * 8,
            &Klds[0][0][0][0] + (size_t)tid * 8);
    #pragma unroll
    for (int ii = 0; ii < 2; ++ii) {
        const int idx = ii * 256 + tid;
        const int d = idx >> 3, xx = idx & 7;
        const int c = xx ^ (d & 7);
        gload16(Vg + (size_t)d * NNp + c * 8, &Vlds[0][idx * 8]);
    }
    __syncthreads();

    int cur = 0;
    for (int t = 0; t < 36; ++t) {
        if (t < 35) {
            const int m0 = (t + 1) * 64;
            gload16(Yt + (bG + m0 + (tid & 63)) * QKVC + h * 128 + 32 + (tid >> 6) * 8,
                    &Klds[cur ^ 1][0][0][0] + (size_t)tid * 8);
            #pragma unroll
            for (int ii = 0; ii < 2; ++ii) {
                const int idx = ii * 256 + tid;
                const int d = idx >> 3, xx = idx & 7;
                const int c = xx ^ (d & 7);
                gload16(Vg + (size_t)d * NNp + m0 + c * 8, &Vlds[cur ^ 1][idx * 8]);
            }
        }

        // ---- S = Q K^T ----
        f32x4 sac[4];
        #pragma unroll
        for (int j = 0; j < 4; ++j) {
            const bf16x8 kf = *(const bf16x8*)&Klds[cur][g][16 * j + i16][0];
            sac[j] = __builtin_amdgcn_mfma_f32_16x16x32_bf16(qfrag, kf, zero, 0, 0, 0);
        }

        // ---- online softmax (rows n = g*4+r, cols m = 16j+i16) ----
        float p[4][4];
        float facr[4];
        #pragma unroll
        for (int r = 0; r < 4; ++r) {
            float m1 = fmaxf(fmaxf(sac[0][r], sac[1][r]), fmaxf(sac[2][r], sac[3][r]));
            m1 = fmaxf(m1, __shfl_xor(m1, 1));
            m1 = fmaxf(m1, __shfl_xor(m1, 2));
            m1 = fmaxf(m1, __shfl_xor(m1, 4));
            m1 = fmaxf(m1, __shfl_xor(m1, 8));
            const float mn = fmaxf(m_run[r], m1);
            const float fc = __expf(m_run[r] - mn);
            m_run[r] = mn;
            facr[r] = fc;
            float ps = 0.f;
            #pragma unroll
            for (int j = 0; j < 4; ++j) { p[j][r] = __expf(sac[j][r] - mn); ps += p[j][r]; }
            ps += __shfl_xor(ps, 1);
            ps += __shfl_xor(ps, 2);
            ps += __shfl_xor(ps, 4);
            ps += __shfl_xor(ps, 8);
            l_run[r] = l_run[r] * fc + ps;
        }

        if (i16 < 4) {
            const float fv = (i16 == 0) ? facr[0] : (i16 == 1) ? facr[1]
                           : (i16 == 2) ? facr[2] : facr[3];
            Fac[wid][g * 4 + i16] = fv;
        }

        // ---- P -> LDS bf16 (chunk-XOR swizzled, padded rows) ----
        {
            const int hi = i16 >> 3, lo = i16 & 7;
            #pragma unroll
            for (int r = 0; r < 4; ++r) {
                const int n  = g * 4 + r;
                const int vs = (g << 1) | (r & 1);
                #pragma unroll
                for (int j = 0; j < 4; ++j) {
                    const int ch = (2 * j + hi) ^ vs;
                    Plds[wid][n][ch * 8 + lo] = f2bf(p[j][r]);
                }
            }
        }

        const float facn = Fac[wid][i16];
        #pragma unroll
        for (int d = 0; d < 4; ++d) {
            oacc[d][0] *= facn; oacc[d][1] *= facn;
            oacc[d][2] *= facn; oacc[d][3] *= facn;
        }

        // ---- O += V * P^T ----
        const int vswp = ((i16 >> 2) << 1) | (i16 & 1);
        const int d7   = i16 & 7;
        #pragma unroll
        for (int s = 0; s < 2; ++s) {
            const int pch = (4 * s + g) ^ vswp;
            const bf16x8 pf = *(const bf16x8*)&Plds[wid][i16][pch * 8];
            const int vch = (4 * s + g) ^ d7;
            #pragma unroll
            for (int db = 0; db < 4; ++db) {
                const bf16x8 vf = *(const bf16x8*)&Vlds[cur][(db * 16 + i16) * 64 + vch * 8];
                oacc[db] = __builtin_amdgcn_mfma_f32_16x16x32_bf16(vf, pf, oacc[db], 0, 0, 0);
            }
        }

        __syncthreads();
        cur ^= 1;
    }

    if (i16 < 4) {
        const float lv = (i16 == 0) ? l_run[0] : (i16 == 1) ? l_run[1]
                       : (i16 == 2) ? l_run[2] : l_run[3];
        Fac[wid][g * 4 + i16] = 1.f / lv;
    }
    __syncthreads();
    const float linv = Fac[wid][i16];
    u16* ob = Ot + (bG + nq) * Cc + h * 64;
    #pragma unroll
    for (int db = 0; db < 4; ++db) {
        u32 lo = (u32)f2bf(oacc[db][0] * linv) | ((u32)f2bf(oacc[db][1] * linv) << 16);
        u32 hi = (u32)f2bf(oacc[db][2] * linv) | ((u32)f2bf(oacc[db][3] * linv) << 16);
        *(uint2*)(ob + db * 16 + g * 4) = make_uint2(lo, hi);
    }
}

// ---------------------------------------------------------------------------
// pe: Ot[(b,n)][c] += BN(dwconv3x3(v)), v from Yt channels h*128+64..127.
// Block: 32 spatial x 8 channel-chunks (h fixed).
// ---------------------------------------------------------------------------
__global__ __launch_bounds__(256)
void pe_bn(const u16* __restrict__ Yt, const float* __restrict__ pw,
           const float* __restrict__ gg, const float* __restrict__ bb,
           const float* __restrict__ mm, const float* __restrict__ vv,
           u16* __restrict__ Ot)
{
    const int tid = threadIdx.x;
    const int h = blockIdx.y, b = blockIdx.z;
    const int p = blockIdx.x * 32 + (tid >> 3);
    const int ch = tid & 7;
    const int c0 = h * 64 + ch * 8;
    const int yy = p / Ww, xx = p - yy * Ww;

    float acc[8];
    #pragma unroll
    for (int j = 0; j < 8; ++j) acc[j] = 0.f;

    #pragma unroll
    for (int dy = -1; dy <= 1; ++dy) {
        const int Y = yy + dy;
        if (Y < 0 || Y >= Hh) continue;
        #pragma unroll
        for (int dx = -1; dx <= 1; ++dx) {
            const int X = xx + dx;
            if (X < 0 || X >= Ww) continue;
            const uint4 raw = *(const uint4*)(Yt +
                ((size_t)b * NNp + Y * Ww + X) * QKVC + h * 128 + 64 + ch * 8);
            const u32* rw = (const u32*)&raw;
            #pragma unroll
            for (int j = 0; j < 8; ++j) {
                const u16 hv = (u16)(rw[j >> 1] >> (16 * (j & 1)));
                acc[j] += pw[(size_t)(c0 + j) * 9 + (dy + 1) * 3 + (dx + 1)] * bf2f(hv);
            }
        }
    }

    u16* dst = Ot + ((size_t)b * NNp + p) * Cc + c0;
    uint4 old = *(uint4*)dst;
    u32* ow = (u32*)&old;
    u32 res[4];
    #pragma unroll
    for (int e = 0; e < 4; ++e) {
        u16 r0, r1;
        {
            const int j = 2 * e;
            const float s = gg[c0 + j] * rsqrtf(vv[c0 + j] + EPSf);
            const float t = bb[c0 + j] - mm[c0 + j] * s;
            r0 = f2bf(bf2f((u16)(ow[e] & 0xffff)) + acc[j] * s + t);
        }
        {
            const int j = 2 * e + 1;
            const float s = gg[c0 + j] * rsqrtf(vv[c0 + j] + EPSf);
            const float t = bb[c0 + j] - mm[c0 + j] * s;
            r1 = f2bf(bf2f((u16)(ow[e] >> 16)) + acc[j] * s + t);
        }
        res[e] = (u32)r0 | ((u32)r1 << 16);
    }
    *(uint4*)dst = make_uint4(res[0], res[1], res[2], res[3]);
}

// ---------------------------------------------------------------------------
extern "C" void kernel_launch(void* const* d_in, const int* in_sizes, int n_in,
                              void* d_out, int out_size, void* d_ws, size_t ws_size,
                              hipStream_t stream)
{
    const float* x      = (const float*)d_in[0];
    const float* qkv_w  = (const float*)d_in[1];
    const float* qkv_g  = (const float*)d_in[2];
    const float* qkv_b  = (const float*)d_in[3];
    const float* qkv_m  = (const float*)d_in[4];
    const float* qkv_v  = (const float*)d_in[5];
    const float* pe_w   = (const float*)d_in[6];
    const float* pe_g   = (const float*)d_in[7];
    const float* pe_b   = (const float*)d_in[8];
    const float* pe_m   = (const float*)d_in[9];
    const float* pe_v   = (const float*)d_in[10];
    const float* proj_w = (const float*)d_in[11];
    const float* proj_g = (const float*)d_in[12];
    const float* proj_b = (const float*)d_in[13];
    const float* proj_m = (const float*)d_in[14];
    const float* proj_v = (const float*)d_in[15];
    const float* f1_w   = (const float*)d_in[16];
    const float* f1_g   = (const float*)d_in[17];
    const float* f1_b   = (const float*)d_in[18];
    const float* f1_m   = (const float*)d_in[19];
    const float* f1_v   = (const float*)d_in[20];
    const float* f2_w   = (const float*)d_in[21];
    const float* f2_g   = (const float*)d_in[22];
    const float* f2_b   = (const float*)d_in[23];
    const float* f2_m   = (const float*)d_in[24];
    const float* f2_v   = (const float*)d_in[25];

    char* wsb = (char*)d_ws;
    u16*   Yt   = (u16*)(wsb);                      //  9,437,184 B (alias Ft)
    u16*   Xt   = (u16*)(wsb + 9437184);            //  4,718,592 B (alias X1t)
    u16*   Vb   = (u16*)(wsb + 14155776);           //  4,718,592 B
    u16*   Ot   = (u16*)(wsb + 18874368);           //  4,718,592 B
    float* x1f  = (float*)(wsb + 23592960);         //  9,437,184 B
    u16*   Wq   = (u16*)(wsb + 33030144);           //    262,144 B
    u16*   Wp   = (u16*)(wsb + 33292288);           //    131,072 B
    u16*   W1   = (u16*)(wsb + 33423360);           //    262,144 B
    u16*   W2   = (u16*)(wsb + 33685504);           //    262,144 B
    float* biq  = (float*)(wsb + 33947648);         //      2,048 B
    float* bip  = (float*)(wsb + 33949696);         //      1,024 B
    float* bi1  = (float*)(wsb + 33950720);         //      2,048 B
    float* bi2  = (float*)(wsb + 33952768);         //      1,024 B
    u16*   Ft   = Yt;
    u16*   X1t  = Xt;
    float* out  = (float*)d_out;

    // weight prep + input transpose
    prep_w<<<dim3(512), dim3(64), 0, stream>>>(qkv_w, qkv_g, qkv_b, qkv_m, qkv_v, Wq, biq, 256, 1);
    prep_w<<<dim3(256), dim3(64), 0, stream>>>(proj_w, proj_g, proj_b, proj_m, proj_v, Wp, bip, 256, 0);
    prep_w<<<dim3(512), dim3(64), 0, stream>>>(f1_w, f1_g, f1_b, f1_m, f1_v, W1, bi1, 256, 0);
    prep_w<<<dim3(256), dim3(64), 0, stream>>>(f2_w, f2_g, f2_b, f2_m, f2_v, W2, bi2, 512, 0);
    cvt_x<<<dim3(36, 4, 4), dim3(256), 0, stream>>>(x, Xt);

    // qkv = fold(BN) o conv1x1
    gemm_mfma<128, 4, 0><<<dim3(72, 4), dim3(256), 0, stream>>>(
        Wq, Xt, biq, nullptr, nullptr, Yt, QKVC, 256);

    // V transpose, attention, pe
    repack_v<<<dim3(36, 4, 4), dim3(256), 0, stream>>>(Yt, Vb);
    attn_mfma<<<dim3(36, 4, 4), dim3(256), 0, stream>>>(Yt, Vb, Ot);
    pe_bn<<<dim3(72, 4, 4), dim3(256), 0, stream>>>(Yt, pe_w, pe_g, pe_b, pe_m, pe_v, Ot);

    // proj (+x residual) -> x1f fp32 + X1t bf16
    gemm_mfma<64, 2, 1><<<dim3(144, 2), dim3(256), 0, stream>>>(
        Wp, Ot, bip, x, x1f, X1t, Cc, 256);

    // f1 + SiLU -> Ft bf16
    gemm_mfma<128, 4, 2><<<dim3(72, 4), dim3(256), 0, stream>>>(
        W1, X1t, bi1, nullptr, nullptr, Ft, QKVC, 256);

    // f2 (+x1f residual) -> out fp32
    gemm_mfma<64, 2, 3><<<dim3(144, 2), dim3(256), 0, stream>>>(
        W2, Ft, bi2, x1f, out, nullptr, Cc, 512);
}

// Round 4
// 163.396 us; speedup vs baseline: 5.9801x; 1.1894x over previous
//
#include <hip/hip_runtime.h>
#include <math.h>

#define Bb   4
#define Cc   256
#define Hh   48
#define Ww   48
#define NNp  2304          // H*W
#define Rr   9216          // B*N
#define NHd  4
#define QKVC 512
#define EPSf 1e-3f

typedef unsigned int   u32;
typedef unsigned short u16;
typedef __attribute__((ext_vector_type(8))) __bf16 bf16x8;
typedef __attribute__((ext_vector_type(4))) float  f32x4;

#if __has_builtin(__builtin_amdgcn_exp2f)
#define EXP2F(x) __builtin_amdgcn_exp2f(x)
#else
#define EXP2F(x) __expf((x) * 0.6931471805599453f)
#endif

__device__ __forceinline__ u16 f2bf(float f) {
    u32 u = __float_as_uint(f);
    u = (u + 0x7fffu + ((u >> 16) & 1u)) >> 16;
    return (u16)u;
}
__device__ __forceinline__ float bf2f(u16 h) {
    return __uint_as_float((u32)h << 16);
}
__device__ __forceinline__ u32 pk2bf(float a, float b) {
    union { __bf16 h; u16 u; } ua, ub;
    ua.h = (__bf16)a; ub.h = (__bf16)b;
    return (u32)ua.u | ((u32)ub.u << 16);
}
__device__ __forceinline__ void gload16(const void* gsrc, void* ldst) {
    __builtin_amdgcn_global_load_lds(
        (const __attribute__((address_space(1))) u32*)gsrc,
        (__attribute__((address_space(3))) u32*)ldst, 16, 0, 0);
}

// ---------------------------------------------------------------------------
// Weight prep: Wb[oc][k] = bf16(W*s*c), bias[oc] = (b - m*s)*c.
// qmode==1: c = log2(e)/sqrt(32) for q channels (oc%128 < 32), else 1.
// (log2e fold lets attention use native v_exp_f32 = exp2 directly.)
// ---------------------------------------------------------------------------
__global__ __launch_bounds__(64)
void prep_w(const float* __restrict__ W, const float* __restrict__ g,
            const float* __restrict__ b, const float* __restrict__ m,
            const float* __restrict__ v, u16* __restrict__ Wb,
            float* __restrict__ bias, int K, int qmode)
{
    const int oc = blockIdx.x;
    const int lane = threadIdx.x;
    const float s = g[oc] * rsqrtf(v[oc] + EPSf);
    const float c = (qmode == 1 && (oc & 127) < 32)
                  ? (0.17677669529663687f * 1.4426950408889634f) : 1.f;
    if (lane == 0) bias[oc] = (b[oc] - m[oc] * s) * c;
    const float sc = s * c;
    for (int k0 = lane * 4; k0 < K; k0 += 256) {
        const float4 w = *(const float4*)(W + (size_t)oc * K + k0);
        u32 lo = (u32)f2bf(w.x * sc) | ((u32)f2bf(w.y * sc) << 16);
        u32 hi = (u32)f2bf(w.z * sc) | ((u32)f2bf(w.w * sc) << 16);
        *(uint2*)(Wb + (size_t)oc * K + k0) = make_uint2(lo, hi);
    }
}

// ---------------------------------------------------------------------------
// x (b,c,n) fp32 -> Xt [(b,n)][256] bf16 (transpose)
// ---------------------------------------------------------------------------
__global__ __launch_bounds__(256)
void cvt_x(const float* __restrict__ x, u16* __restrict__ Xt)
{
    const int b = blockIdx.z, c0 = blockIdx.y * 64, n0 = blockIdx.x * 64;
    __shared__ float tile[64][65];
    const int tid = threadIdx.x;
    {
        const int n = tid & 63, cl = tid >> 6;
        #pragma unroll
        for (int cc = 0; cc < 16; ++cc) {
            const int c = cc * 4 + cl;
            tile[c][n] = x[((size_t)b * Cc + c0 + c) * NNp + n0 + n];
        }
    }
    __syncthreads();
    {
        const int n = tid >> 2, q = tid & 3;
        #pragma unroll
        for (int j = 0; j < 2; ++j) {
            const int ch = q * 2 + j, c = ch * 8;
            u32 w[4];
            #pragma unroll
            for (int e = 0; e < 4; ++e)
                w[e] = (u32)f2bf(tile[c + 2*e][n]) | ((u32)f2bf(tile[c + 2*e + 1][n]) << 16);
            *(uint4*)(Xt + ((size_t)b * NNp + n0 + n) * Cc + c0 + c)
                = make_uint4(w[0], w[1], w[2], w[3]);
        }
    }
}

// ---------------------------------------------------------------------------
// MFMA GEMM:  Y[(b,n)][oc] = epi( sum_k Wb[oc][k] * Xt[(b,n)][k] )
// MODE 0: bf16 out (qkv)      MODE 1: +x resid, fp32 out + bf16 out (proj)
// MODE 2: SiLU, bf16 out (f1) MODE 3: +resid, fp32 out only (f2)
// ---------------------------------------------------------------------------
template<int BN_, int FN_, int MODE>
__global__ __launch_bounds__(256)
void gemm_mfma(const u16* __restrict__ A, const u16* __restrict__ Bx,
               const float* __restrict__ bias, const float* __restrict__ resid,
               float* __restrict__ Yf, u16* __restrict__ Yt, int M, int K)
{
    constexpr int WN = FN_ * 16;
    const int r0 = blockIdx.x * BN_;
    const int m0 = blockIdx.y * 128;
    const int tid = threadIdx.x;
    const int lane = tid & 63, wid = tid >> 6;
    const int g = lane >> 4, i16 = lane & 15;
    const int wr = wid >> 1, wc = wid & 1;

    __shared__ __align__(16) u16 Al[4][128][8];
    __shared__ __align__(16) u16 Bl[4][BN_][8];

    f32x4 acc[4][FN_];
    #pragma unroll
    for (int i = 0; i < 4; ++i)
        #pragma unroll
        for (int j = 0; j < FN_; ++j) acc[i][j] = (f32x4){0.f, 0.f, 0.f, 0.f};

    for (int k0 = 0; k0 < K; k0 += 32) {
        #pragma unroll
        for (int ii = 0; ii < 2; ++ii) {
            const int ci = ii * 256 + tid;
            gload16(A + (size_t)(m0 + (ci & 127)) * K + k0 + (ci >> 7) * 8,
                    &Al[0][0][0] + (size_t)ci * 8);
        }
        if (BN_ == 128) {
            #pragma unroll
            for (int ii = 0; ii < 2; ++ii) {
                const int ci = ii * 256 + tid;
                gload16(Bx + (size_t)(r0 + (ci & 127)) * K + k0 + (ci >> 7) * 8,
                        &Bl[0][0][0] + (size_t)ci * 8);
            }
        } else {
            gload16(Bx + (size_t)(r0 + (tid & 63)) * K + k0 + (tid >> 6) * 8,
                    &Bl[0][0][0] + (size_t)tid * 8);
        }
        __syncthreads();
        bf16x8 af[4], bf[FN_];
        #pragma unroll
        for (int ao = 0; ao < 4; ++ao)
            af[ao] = *(const bf16x8*)&Al[g][wr * 64 + ao * 16 + i16][0];
        #pragma unroll
        for (int bo = 0; bo < FN_; ++bo)
            bf[bo] = *(const bf16x8*)&Bl[g][wc * WN + bo * 16 + i16][0];
        #pragma unroll
        for (int ao = 0; ao < 4; ++ao)
            #pragma unroll
            for (int bo = 0; bo < FN_; ++bo)
                acc[ao][bo] = __builtin_amdgcn_mfma_f32_16x16x32_bf16(
                    af[ao], bf[bo], acc[ao][bo], 0, 0, 0);
        __syncthreads();
    }

    const int b  = r0 / NNp;
    const int nb = r0 - b * NNp;
    #pragma unroll
    for (int ao = 0; ao < 4; ++ao) {
        const int oc0 = m0 + wr * 64 + ao * 16 + g * 4;
        const float4 t4 = *(const float4*)(bias + oc0);
        #pragma unroll
        for (int bo = 0; bo < FN_; ++bo) {
            const int nloc = wc * WN + bo * 16 + i16;
            float y[4];
            y[0] = acc[ao][bo][0] + t4.x;  y[1] = acc[ao][bo][1] + t4.y;
            y[2] = acc[ao][bo][2] + t4.z;  y[3] = acc[ao][bo][3] + t4.w;
            if (MODE == 1 || MODE == 3) {
                const int n = nb + nloc;
                const size_t base = ((size_t)b * M + oc0) * NNp + n;
                #pragma unroll
                for (int r = 0; r < 4; ++r) {
                    y[r] += resid[base + (size_t)r * NNp];
                    Yf[base + (size_t)r * NNp] = y[r];
                }
            }
            if (MODE == 2) {
                #pragma unroll
                for (int r = 0; r < 4; ++r) y[r] = y[r] / (1.f + __expf(-y[r]));
            }
            if (MODE != 3) {
                const size_t rG = (size_t)(r0 + nloc);
                u32 lo = (u32)f2bf(y[0]) | ((u32)f2bf(y[1]) << 16);
                u32 hi = (u32)f2bf(y[2]) | ((u32)f2bf(y[3]) << 16);
                *(uint2*)(Yt + rG * M + oc0) = make_uint2(lo, hi);
            }
        }
    }
}

// ---------------------------------------------------------------------------
// V transpose: Yt [(b,n)][512] (v = ch h*128+64..127) -> Vb[bh][64][2304]
// ---------------------------------------------------------------------------
__global__ __launch_bounds__(256)
void repack_v(const u16* __restrict__ Yt, u16* __restrict__ Vb)
{
    const int m0 = blockIdx.x * 64;
    const int h = blockIdx.y, b = blockIdx.z;
    const int bh = b * NHd + h;
    __shared__ u16 vt[64][72];
    const int tid = threadIdx.x;
    #pragma unroll
    for (int ii = 0; ii < 2; ++ii) {
        const int mm = ii * 32 + (tid >> 3);
        const int ch = tid & 7;
        *(uint4*)&vt[mm][ch * 8] =
            *(const uint4*)(Yt + ((size_t)b * NNp + m0 + mm) * QKVC + h * 128 + 64 + ch * 8);
    }
    __syncthreads();
    const int d = tid >> 2, mq = tid & 3;
    #pragma unroll
    for (int j = 0; j < 2; ++j) {
        const int mc = mq * 2 + j;
        u32 w[4];
        #pragma unroll
        for (int e = 0; e < 4; ++e)
            w[e] = (u32)vt[mc * 8 + 2*e][d] | ((u32)vt[mc * 8 + 2*e + 1][d] << 16);
        *(uint4*)(Vb + ((size_t)bh * 64 + d) * NNp + m0 + mc * 8)
            = make_uint4(w[0], w[1], w[2], w[3]);
    }
}

// ---------------------------------------------------------------------------
// MFMA flash attention, swapped-QK^T form.
// S^T = mfma(K, Q): lane (g,i16) holds S[key=16j+4g+r][q=i16] -> one query
// per lane => lane-local softmax state, 2 shuffles per reduce, defer-max.
// PV: O[d][q] = mfma(V, P); P staged per-wave in LDS u32[16][36].
// ---------------------------------------------------------------------------
__global__ __launch_bounds__(256)
void attn_mfma(const u16* __restrict__ Yt, const u16* __restrict__ Vb,
               u16* __restrict__ Ot)
{
    __shared__ __align__(16) u16 Klds[2][4][64][8];
    __shared__ __align__(16) u16 Vlds[2][64 * 64];
    __shared__ __align__(16) u32 Plds[4][16][36];

    const int tid  = threadIdx.x;
    const int wid  = tid >> 6;
    const int lane = tid & 63;
    const int g    = lane >> 4;
    const int i16  = lane & 15;

    const int h = blockIdx.y, b = blockIdx.z;
    const int bh = b * NHd + h;
    const size_t bG = (size_t)b * NNp;
    const u16* Vg = Vb + (size_t)bh * 64 * NNp;

    const int nq = blockIdx.x * 64 + wid * 16 + i16;
    const bf16x8 qfrag = *(const bf16x8*)(Yt + (bG + nq) * QKVC + h * 128 + g * 8);

    f32x4 zero = {0.f, 0.f, 0.f, 0.f};
    f32x4 oacc[4];
    #pragma unroll
    for (int d = 0; d < 4; ++d) oacc[d] = zero;
    float m_run = -1e30f, l_run = 0.f;

    // stage tile 0
    gload16(Yt + (bG + (tid & 63)) * QKVC + h * 128 + 32 + (tid >> 6) * 8,
            &Klds[0][0][0][0] + (size_t)tid * 8);
    #pragma unroll
    for (int ii = 0; ii < 2; ++ii) {
        const int idx = ii * 256 + tid;
        const int d = idx >> 3, xx = idx & 7;
        const int c = xx ^ (d & 7);
        gload16(Vg + (size_t)d * NNp + c * 8, &Vlds[0][idx * 8]);
    }
    __syncthreads();

    int cur = 0;
    for (int t = 0; t < 36; ++t) {
        if (t < 35) {
            const int m0 = (t + 1) * 64;
            gload16(Yt + (bG + m0 + (tid & 63)) * QKVC + h * 128 + 32 + (tid >> 6) * 8,
                    &Klds[cur ^ 1][0][0][0] + (size_t)tid * 8);
            #pragma unroll
            for (int ii = 0; ii < 2; ++ii) {
                const int idx = ii * 256 + tid;
                const int d = idx >> 3, xx = idx & 7;
                const int c = xx ^ (d & 7);
                gload16(Vg + (size_t)d * NNp + m0 + c * 8, &Vlds[cur ^ 1][idx * 8]);
            }
        }

        // ---- S^T = K Q^T : lane holds keys 16j+4g+r for query i16 ----
        f32x4 sac[4];
        __builtin_amdgcn_s_setprio(1);
        #pragma unroll
        for (int j = 0; j < 4; ++j) {
            const bf16x8 kf = *(const bf16x8*)&Klds[cur][g][16 * j + i16][0];
            sac[j] = __builtin_amdgcn_mfma_f32_16x16x32_bf16(kf, qfrag, zero, 0, 0, 0);
        }
        __builtin_amdgcn_s_setprio(0);

        // ---- lane-local online softmax (log2 domain) ----
        float pm = sac[0][0];
        #pragma unroll
        for (int j = 0; j < 4; ++j)
            #pragma unroll
            for (int r = 0; r < 4; ++r) pm = fmaxf(pm, sac[j][r]);
        pm = fmaxf(pm, __shfl_xor(pm, 16));
        pm = fmaxf(pm, __shfl_xor(pm, 32));

        if (!__all(pm <= m_run + 8.f)) {        // defer-max (THR=8 log2 units)
            const float mn = fmaxf(m_run, pm);
            const float fc = EXP2F(m_run - mn);
            m_run = mn;
            l_run *= fc;
            #pragma unroll
            for (int d = 0; d < 4; ++d) {
                oacc[d][0] *= fc; oacc[d][1] *= fc;
                oacc[d][2] *= fc; oacc[d][3] *= fc;
            }
        }

        float p[4][4];
        float psum = 0.f;
        #pragma unroll
        for (int j = 0; j < 4; ++j)
            #pragma unroll
            for (int r = 0; r < 4; ++r) {
                p[j][r] = EXP2F(sac[j][r] - m_run);
                psum += p[j][r];
            }
        psum += __shfl_xor(psum, 16);
        psum += __shfl_xor(psum, 32);
        l_run += psum;

        // ---- P -> per-wave LDS row [q=i16], u32 cols 8j+2g(+1) ----
        {
            u32* prow = &Plds[wid][i16][0];
            #pragma unroll
            for (int j = 0; j < 4; ++j) {
                const u32 w0 = pk2bf(p[j][0], p[j][1]);
                const u32 w1 = pk2bf(p[j][2], p[j][3]);
                *(uint2*)&prow[8 * j + 2 * g] = make_uint2(w0, w1);
            }
        }

        // ---- O += V P : keys 32s+8g+t per fragment ----
        const int d7 = i16 & 7;
        __builtin_amdgcn_s_setprio(1);
        #pragma unroll
        for (int s = 0; s < 2; ++s) {
            const bf16x8 pf = *(const bf16x8*)&Plds[wid][i16][16 * s + 4 * g];
            const int vch = (4 * s + g) ^ d7;
            #pragma unroll
            for (int db = 0; db < 4; ++db) {
                const bf16x8 vf = *(const bf16x8*)&Vlds[cur][(db * 16 + i16) * 64 + vch * 8];
                oacc[db] = __builtin_amdgcn_mfma_f32_16x16x32_bf16(vf, pf, oacc[db], 0, 0, 0);
            }
        }
        __builtin_amdgcn_s_setprio(0);

        __syncthreads();
        cur ^= 1;
    }

    // epilogue: lane-local 1/l, store O[d][q=i16]
    const float linv = 1.f / l_run;
    u16* ob = Ot + (bG + nq) * Cc + h * 64;
    #pragma unroll
    for (int db = 0; db < 4; ++db) {
        u32 lo = (u32)f2bf(oacc[db][0] * linv) | ((u32)f2bf(oacc[db][1] * linv) << 16);
        u32 hi = (u32)f2bf(oacc[db][2] * linv) | ((u32)f2bf(oacc[db][3] * linv) << 16);
        *(uint2*)(ob + db * 16 + g * 4) = make_uint2(lo, hi);
    }
}

// ---------------------------------------------------------------------------
// pe: Ot[(b,n)][c] += BN(dwconv3x3(v)), v from Yt channels h*128+64..127.
// ---------------------------------------------------------------------------
__global__ __launch_bounds__(256)
void pe_bn(const u16* __restrict__ Yt, const float* __restrict__ pw,
           const float* __restrict__ gg, const float* __restrict__ bb,
           const float* __restrict__ mm, const float* __restrict__ vv,
           u16* __restrict__ Ot)
{
    const int tid = threadIdx.x;
    const int h = blockIdx.y, b = blockIdx.z;
    const int p = blockIdx.x * 32 + (tid >> 3);
    const int ch = tid & 7;
    const int c0 = h * 64 + ch * 8;
    const int yy = p / Ww, xx = p - yy * Ww;

    float acc[8];
    #pragma unroll
    for (int j = 0; j < 8; ++j) acc[j] = 0.f;

    #pragma unroll
    for (int dy = -1; dy <= 1; ++dy) {
        const int Y = yy + dy;
        if (Y < 0 || Y >= Hh) continue;
        #pragma unroll
        for (int dx = -1; dx <= 1; ++dx) {
            const int X = xx + dx;
            if (X < 0 || X >= Ww) continue;
            const uint4 raw = *(const uint4*)(Yt +
                ((size_t)b * NNp + Y * Ww + X) * QKVC + h * 128 + 64 + ch * 8);
            const u32* rw = (const u32*)&raw;
            #pragma unroll
            for (int j = 0; j < 8; ++j) {
                const u16 hv = (u16)(rw[j >> 1] >> (16 * (j & 1)));
                acc[j] += pw[(size_t)(c0 + j) * 9 + (dy + 1) * 3 + (dx + 1)] * bf2f(hv);
            }
        }
    }

    u16* dst = Ot + ((size_t)b * NNp + p) * Cc + c0;
    uint4 old = *(uint4*)dst;
    u32* ow = (u32*)&old;
    u32 res[4];
    #pragma unroll
    for (int e = 0; e < 4; ++e) {
        u16 r0, r1;
        {
            const int j = 2 * e;
            const float s = gg[c0 + j] * rsqrtf(vv[c0 + j] + EPSf);
            const float t = bb[c0 + j] - mm[c0 + j] * s;
            r0 = f2bf(bf2f((u16)(ow[e] & 0xffff)) + acc[j] * s + t);
        }
        {
            const int j = 2 * e + 1;
            const float s = gg[c0 + j] * rsqrtf(vv[c0 + j] + EPSf);
            const float t = bb[c0 + j] - mm[c0 + j] * s;
            r1 = f2bf(bf2f((u16)(ow[e] >> 16)) + acc[j] * s + t);
        }
        res[e] = (u32)r0 | ((u32)r1 << 16);
    }
    *(uint4*)dst = make_uint4(res[0], res[1], res[2], res[3]);
}

// ---------------------------------------------------------------------------
extern "C" void kernel_launch(void* const* d_in, const int* in_sizes, int n_in,
                              void* d_out, int out_size, void* d_ws, size_t ws_size,
                              hipStream_t stream)
{
    const float* x      = (const float*)d_in[0];
    const float* qkv_w  = (const float*)d_in[1];
    const float* qkv_g  = (const float*)d_in[2];
    const float* qkv_b  = (const float*)d_in[3];
    const float* qkv_m  = (const float*)d_in[4];
    const float* qkv_v  = (const float*)d_in[5];
    const float* pe_w   = (const float*)d_in[6];
    const float* pe_g   = (const float*)d_in[7];
    const float* pe_b   = (const float*)d_in[8];
    const float* pe_m   = (const float*)d_in[9];
    const float* pe_v   = (const float*)d_in[10];
    const float* proj_w = (const float*)d_in[11];
    const float* proj_g = (const float*)d_in[12];
    const float* proj_b = (const float*)d_in[13];
    const float* proj_m = (const float*)d_in[14];
    const float* proj_v = (const float*)d_in[15];
    const float* f1_w   = (const float*)d_in[16];
    const float* f1_g   = (const float*)d_in[17];
    const float* f1_b   = (const float*)d_in[18];
    const float* f1_m   = (const float*)d_in[19];
    const float* f1_v   = (const float*)d_in[20];
    const float* f2_w   = (const float*)d_in[21];
    const float* f2_g   = (const float*)d_in[22];
    const float* f2_b   = (const float*)d_in[23];
    const float* f2_m   = (const float*)d_in[24];
    const float* f2_v   = (const float*)d_in[25];

    char* wsb = (char*)d_ws;
    u16*   Yt   = (u16*)(wsb);                      //  9,437,184 B (alias Ft)
    u16*   Xt   = (u16*)(wsb + 9437184);            //  4,718,592 B (alias X1t)
    u16*   Vb   = (u16*)(wsb + 14155776);           //  4,718,592 B
    u16*   Ot   = (u16*)(wsb + 18874368);           //  4,718,592 B
    float* x1f  = (float*)(wsb + 23592960);         //  9,437,184 B
    u16*   Wq   = (u16*)(wsb + 33030144);
    u16*   Wp   = (u16*)(wsb + 33292288);
    u16*   W1   = (u16*)(wsb + 33423360);
    u16*   W2   = (u16*)(wsb + 33685504);
    float* biq  = (float*)(wsb + 33947648);
    float* bip  = (float*)(wsb + 33949696);
    float* bi1  = (float*)(wsb + 33950720);
    float* bi2  = (float*)(wsb + 33952768);
    u16*   Ft   = Yt;
    u16*   X1t  = Xt;
    float* out  = (float*)d_out;

    prep_w<<<dim3(512), dim3(64), 0, stream>>>(qkv_w, qkv_g, qkv_b, qkv_m, qkv_v, Wq, biq, 256, 1);
    prep_w<<<dim3(256), dim3(64), 0, stream>>>(proj_w, proj_g, proj_b, proj_m, proj_v, Wp, bip, 256, 0);
    prep_w<<<dim3(512), dim3(64), 0, stream>>>(f1_w, f1_g, f1_b, f1_m, f1_v, W1, bi1, 256, 0);
    prep_w<<<dim3(256), dim3(64), 0, stream>>>(f2_w, f2_g, f2_b, f2_m, f2_v, W2, bi2, 512, 0);
    cvt_x<<<dim3(36, 4, 4), dim3(256), 0, stream>>>(x, Xt);

    gemm_mfma<128, 4, 0><<<dim3(72, 4), dim3(256), 0, stream>>>(
        Wq, Xt, biq, nullptr, nullptr, Yt, QKVC, 256);

    repack_v<<<dim3(36, 4, 4), dim3(256), 0, stream>>>(Yt, Vb);
    attn_mfma<<<dim3(36, 4, 4), dim3(256), 0, stream>>>(Yt, Vb, Ot);
    pe_bn<<<dim3(72, 4, 4), dim3(256), 0, stream>>>(Yt, pe_w, pe_g, pe_b, pe_m, pe_v, Ot);

    gemm_mfma<64, 2, 1><<<dim3(144, 2), dim3(256), 0, stream>>>(
        Wp, Ot, bip, x, x1f, X1t, Cc, 256);

    gemm_mfma<128, 4, 2><<<dim3(72, 4), dim3(256), 0, stream>>>(
        W1, X1t, bi1, nullptr, nullptr, Ft, QKVC, 256);

    gemm_mfma<64, 2, 3><<<dim3(144, 2), dim3(256), 0, stream>>>(
        W2, Ft, bi2, x1f, out, nullptr, Cc, 512);
}